// Round 1
// 434.368 us; speedup vs baseline: 1.0104x; 1.0104x over previous
//
#include <hip/hip_runtime.h>

// Sparsemax along last dim of an (ROWS x D) fp32 matrix.
//
// Key bound: sum_{i in support} (x_i - tau) = 1  =>  x_max - tau <= 1,
// so tau* in [max-1, max) and support ⊆ {x >= max-1}. For Gaussian rows
// this candidate set is ~5-10 of 8192 elements. So:
//   pass 1: row max (registers + shuffle reduce)
//   pass 2: gather candidates {x >= max-1} into LDS (tiny)
//   Michelot on the candidate set only (converges from any support superset)
//   epilogue: out = max(x - tau, 0)
// Fallback to full-register Michelot if candidates overflow LDS capacity
// (block-uniform branch; never taken for this input distribution).

#define D 8192
#define BLOCK 256
#define VEC 8  // 8 float4 per thread = 32 elements
#define CAND_CAP 2048

__global__ __launch_bounds__(BLOCK) void sparsemax_kernel(
    const float* __restrict__ x, float* __restrict__ out) {
  const long long row = blockIdx.x;
  const float4* __restrict__ xr = (const float4*)(x + row * (long long)D);
  float4* __restrict__ outr = (float4*)(out + row * (long long)D);
  const int tid = threadIdx.x;
  const int lane = tid & 63;
  const int wave = tid >> 6;

  // Load row into registers, coalesced float4.
  float4 v[VEC];
#pragma unroll
  for (int i = 0; i < VEC; ++i) v[i] = xr[tid + i * BLOCK];

  __shared__ float red_s[4];
  __shared__ float red_c[4];
  __shared__ float sh_bcast;  // row max broadcast
  __shared__ float sh_tau;
  __shared__ float sh_cnt;
  __shared__ int sh_n;
  __shared__ float cand[CAND_CAP];

  // ---- pass 1: row max ----
  float m = -3.402823466e+38f;
#pragma unroll
  for (int i = 0; i < VEC; ++i)
    m = fmaxf(m, fmaxf(fmaxf(v[i].x, v[i].y), fmaxf(v[i].z, v[i].w)));
#pragma unroll
  for (int o = 32; o > 0; o >>= 1) m = fmaxf(m, __shfl_down(m, o, 64));
  if (lane == 0) red_s[wave] = m;
  __syncthreads();
  if (tid == 0) {
    sh_bcast = fmaxf(fmaxf(red_s[0], red_s[1]), fmaxf(red_s[2], red_s[3]));
    sh_n = 0;
  }
  __syncthreads();
  const float t0 = sh_bcast - 1.0f;  // support ⊆ {x >= t0}

  // ---- pass 2: gather candidates into LDS ----
#pragma unroll
  for (int i = 0; i < VEC; ++i) {
    float a0 = v[i].x, a1 = v[i].y, a2 = v[i].z, a3 = v[i].w;
    if (a0 >= t0) { int p = atomicAdd(&sh_n, 1); if (p < CAND_CAP) cand[p] = a0; }
    if (a1 >= t0) { int p = atomicAdd(&sh_n, 1); if (p < CAND_CAP) cand[p] = a1; }
    if (a2 >= t0) { int p = atomicAdd(&sh_n, 1); if (p < CAND_CAP) cand[p] = a2; }
    if (a3 >= t0) { int p = atomicAdd(&sh_n, 1); if (p < CAND_CAP) cand[p] = a3; }
  }
  __syncthreads();
  const int n = sh_n;

  float tau;
  if (n <= CAND_CAP) {
    // ---- Michelot on the candidate set (tiny; ~2-4 iterations) ----
    float cur = -3.402823466e+38f;  // iteration 0 includes all candidates
    float prevc = -1.0f;
    for (int iter = 0; iter < 256; ++iter) {
      float s = 0.f, c = 0.f;
      for (int j = tid; j < n; j += BLOCK) {
        float xv = cand[j];
        if (xv > cur) { s += xv; c += 1.f; }
      }
#pragma unroll
      for (int o = 32; o > 0; o >>= 1) {
        s += __shfl_down(s, o, 64);
        c += __shfl_down(c, o, 64);
      }
      if (lane == 0) { red_s[wave] = s; red_c[wave] = c; }
      __syncthreads();
      if (tid == 0) {
        float ts = (red_s[0] + red_s[1]) + (red_s[2] + red_s[3]);
        float tc = (red_c[0] + red_c[1]) + (red_c[2] + red_c[3]);
        sh_tau = (ts - 1.0f) / tc;  // tc >= 1 (max always in support)
        sh_cnt = tc;
      }
      __syncthreads();
      cur = sh_tau;
      float cnt = sh_cnt;
      if (cnt == prevc) break;  // support stable => tau exact; uniform branch
      prevc = cnt;
    }
    tau = cur;
  } else {
    // ---- fallback: full-register Michelot (original path; rare) ----
    float ps = 0.f;
#pragma unroll
    for (int i = 0; i < VEC; ++i) ps += (v[i].x + v[i].y) + (v[i].z + v[i].w);
#pragma unroll
    for (int o = 32; o > 0; o >>= 1) ps += __shfl_down(ps, o, 64);
    if (lane == 0) red_s[wave] = ps;
    __syncthreads();
    if (tid == 0) {
      float tot = (red_s[0] + red_s[1]) + (red_s[2] + red_s[3]);
      sh_tau = (tot - 1.0f) * (1.0f / (float)D);
    }
    __syncthreads();
    float cur = sh_tau;
    float prevc = (float)D;
    for (int iter = 0; iter < 48; ++iter) {
      float s = 0.f, c = 0.f;
#pragma unroll
      for (int i = 0; i < VEC; ++i) {
        if (v[i].x > cur) { s += v[i].x; c += 1.f; }
        if (v[i].y > cur) { s += v[i].y; c += 1.f; }
        if (v[i].z > cur) { s += v[i].z; c += 1.f; }
        if (v[i].w > cur) { s += v[i].w; c += 1.f; }
      }
#pragma unroll
      for (int o = 32; o > 0; o >>= 1) {
        s += __shfl_down(s, o, 64);
        c += __shfl_down(c, o, 64);
      }
      if (lane == 0) { red_s[wave] = s; red_c[wave] = c; }
      __syncthreads();
      if (tid == 0) {
        float ts = (red_s[0] + red_s[1]) + (red_s[2] + red_s[3]);
        float tc = (red_c[0] + red_c[1]) + (red_c[2] + red_c[3]);
        sh_tau = (ts - 1.0f) / tc;
        sh_cnt = tc;
      }
      __syncthreads();
      cur = sh_tau;
      float cnt = sh_cnt;
      if (cnt == prevc) break;
      prevc = cnt;
    }
    tau = cur;
  }

  // ---- epilogue: out = max(x - tau, 0) ----
#pragma unroll
  for (int i = 0; i < VEC; ++i) {
    float4 o;
    o.x = fmaxf(v[i].x - tau, 0.f);
    o.y = fmaxf(v[i].y - tau, 0.f);
    o.z = fmaxf(v[i].z - tau, 0.f);
    o.w = fmaxf(v[i].w - tau, 0.f);
    outr[tid + i * BLOCK] = o;
  }
}

extern "C" void kernel_launch(void* const* d_in, const int* in_sizes, int n_in,
                              void* d_out, int out_size, void* d_ws, size_t ws_size,
                              hipStream_t stream) {
  const float* x = (const float*)d_in[0];
  float* out = (float*)d_out;
  const int rows = in_sizes[0] / D;  // 8192
  sparsemax_kernel<<<rows, BLOCK, 0, stream>>>(x, out);
}

// Round 2
// 420.238 us; speedup vs baseline: 1.0444x; 1.0336x over previous
//
#include <hip/hip_runtime.h>

// Sparsemax along last dim of an (ROWS x D) fp32 matrix.
//
// Key bound: sum_{i in support} (x_i - tau) = 1  =>  x_max - tau <= 1,
// so tau* in [max-1, max) and support ⊆ {x >= max-1}. For Gaussian rows
// this candidate set is ~5-10 of 8192 elements.
//   pass 1: row max (registers + butterfly shuffle reduce; 1 barrier)
//   pass 2: gather candidates {x >= max-1} into LDS (1 barrier)
//   Michelot on candidates: if n<=64, wave 0 only, lane-per-candidate,
//     butterfly reductions, ZERO block barriers in the loop (1 barrier after)
//   epilogue: out = max(x - tau, 0), nontemporal store
// Fallbacks (block-uniform branches, never taken for Gaussian data):
//   64 < n <= CAND_CAP: block-wide Michelot on LDS candidates
//   n > CAND_CAP:       full-register Michelot
//
// BLOCK=512/VEC=4 keeps data VGPRs at 16 (~48 total) => full 32 waves/CU
// occupancy for HBM latency hiding (VEC=8 risked the 64-VGPR cliff).

#define D 8192
#define BLOCK 512
#define VEC 4  // 4 float4 per thread = 16 elements; 512*16 = 8192
#define NWAVES (BLOCK / 64)
#define CAND_CAP 1024

typedef float floatx4 __attribute__((ext_vector_type(4)));

__global__ __launch_bounds__(BLOCK) void sparsemax_kernel(
    const float* __restrict__ x, float* __restrict__ out) {
  const long long row = blockIdx.x;
  const floatx4* __restrict__ xr = (const floatx4*)(x + row * (long long)D);
  floatx4* __restrict__ outr = (floatx4*)(out + row * (long long)D);
  const int tid = threadIdx.x;
  const int lane = tid & 63;
  const int wave = tid >> 6;

  // Load row into registers, coalesced nontemporal float4.
  floatx4 v[VEC];
#pragma unroll
  for (int i = 0; i < VEC; ++i)
    v[i] = __builtin_nontemporal_load(&xr[tid + i * BLOCK]);

  __shared__ float red_s[NWAVES];
  __shared__ float red_c[NWAVES];
  __shared__ float sh_tau;
  __shared__ float sh_cnt;
  __shared__ int sh_n;
  __shared__ float cand[CAND_CAP];

  // ---- pass 1: row max (butterfly => every lane holds wave max) ----
  float m = -3.402823466e+38f;
#pragma unroll
  for (int i = 0; i < VEC; ++i)
    m = fmaxf(m, fmaxf(fmaxf(v[i].x, v[i].y), fmaxf(v[i].z, v[i].w)));
#pragma unroll
  for (int o = 32; o > 0; o >>= 1) m = fmaxf(m, __shfl_xor(m, o, 64));
  if (lane == 0) red_s[wave] = m;
  if (tid == 0) sh_n = 0;
  __syncthreads();  // barrier 1
  float bm = red_s[0];
#pragma unroll
  for (int w = 1; w < NWAVES; ++w) bm = fmaxf(bm, red_s[w]);
  const float t0 = bm - 1.0f;  // support ⊆ {x >= t0}

  // ---- pass 2: gather candidates into LDS ----
#pragma unroll
  for (int i = 0; i < VEC; ++i) {
    float a0 = v[i].x, a1 = v[i].y, a2 = v[i].z, a3 = v[i].w;
    if (a0 >= t0) { int p = atomicAdd(&sh_n, 1); if (p < CAND_CAP) cand[p] = a0; }
    if (a1 >= t0) { int p = atomicAdd(&sh_n, 1); if (p < CAND_CAP) cand[p] = a1; }
    if (a2 >= t0) { int p = atomicAdd(&sh_n, 1); if (p < CAND_CAP) cand[p] = a2; }
    if (a3 >= t0) { int p = atomicAdd(&sh_n, 1); if (p < CAND_CAP) cand[p] = a3; }
  }
  __syncthreads();  // barrier 2
  const int n = sh_n;

  float tau;
  if (n <= 64) {
    // ---- wave-0-only Michelot: lane-per-candidate, no block barriers ----
    if (wave == 0) {
      float xv = (lane < n) ? cand[lane] : -3.402823466e+38f;
      float cur = -3.402823466e+38f;
      float prevc = -1.0f;
      for (int iter = 0; iter < 64; ++iter) {
        float s = (xv > cur) ? xv : 0.f;
        float c = (xv > cur) ? 1.f : 0.f;
#pragma unroll
        for (int o = 32; o > 0; o >>= 1) {
          s += __shfl_xor(s, o, 64);
          c += __shfl_xor(c, o, 64);
        }
        cur = (s - 1.0f) / c;  // c >= 1 (max always in support)
        if (c == prevc) break;  // support stable => tau exact
        prevc = c;
      }
      if (lane == 0) sh_tau = cur;
    }
    __syncthreads();  // barrier 3
    tau = sh_tau;
  } else if (n <= CAND_CAP) {
    // ---- block-wide Michelot on LDS candidates (rare) ----
    float cur = -3.402823466e+38f;
    float prevc = -1.0f;
    for (int iter = 0; iter < 256; ++iter) {
      float s = 0.f, c = 0.f;
      for (int j = tid; j < n; j += BLOCK) {
        float xv = cand[j];
        if (xv > cur) { s += xv; c += 1.f; }
      }
#pragma unroll
      for (int o = 32; o > 0; o >>= 1) {
        s += __shfl_xor(s, o, 64);
        c += __shfl_xor(c, o, 64);
      }
      if (lane == 0) { red_s[wave] = s; red_c[wave] = c; }
      __syncthreads();
      if (tid == 0) {
        float ts = 0.f, tc = 0.f;
#pragma unroll
        for (int w = 0; w < NWAVES; ++w) { ts += red_s[w]; tc += red_c[w]; }
        sh_tau = (ts - 1.0f) / tc;
        sh_cnt = tc;
      }
      __syncthreads();
      cur = sh_tau;
      float cnt = sh_cnt;
      if (cnt == prevc) break;
      prevc = cnt;
    }
    tau = cur;
  } else {
    // ---- full-register Michelot fallback (pathological; never on Gaussian) ----
    float ps = 0.f;
#pragma unroll
    for (int i = 0; i < VEC; ++i) ps += (v[i].x + v[i].y) + (v[i].z + v[i].w);
#pragma unroll
    for (int o = 32; o > 0; o >>= 1) ps += __shfl_xor(ps, o, 64);
    if (lane == 0) red_s[wave] = ps;
    __syncthreads();
    if (tid == 0) {
      float tot = 0.f;
#pragma unroll
      for (int w = 0; w < NWAVES; ++w) tot += red_s[w];
      sh_tau = (tot - 1.0f) * (1.0f / (float)D);
    }
    __syncthreads();
    float cur = sh_tau;
    float prevc = (float)D;
    for (int iter = 0; iter < 48; ++iter) {
      float s = 0.f, c = 0.f;
#pragma unroll
      for (int i = 0; i < VEC; ++i) {
        if (v[i].x > cur) { s += v[i].x; c += 1.f; }
        if (v[i].y > cur) { s += v[i].y; c += 1.f; }
        if (v[i].z > cur) { s += v[i].z; c += 1.f; }
        if (v[i].w > cur) { s += v[i].w; c += 1.f; }
      }
#pragma unroll
      for (int o = 32; o > 0; o >>= 1) {
        s += __shfl_xor(s, o, 64);
        c += __shfl_xor(c, o, 64);
      }
      if (lane == 0) { red_s[wave] = s; red_c[wave] = c; }
      __syncthreads();
      if (tid == 0) {
        float ts = 0.f, tc = 0.f;
#pragma unroll
        for (int w = 0; w < NWAVES; ++w) { ts += red_s[w]; tc += red_c[w]; }
        sh_tau = (ts - 1.0f) / tc;
        sh_cnt = tc;
      }
      __syncthreads();
      cur = sh_tau;
      float cnt = sh_cnt;
      if (cnt == prevc) break;
      prevc = cnt;
    }
    tau = cur;
  }

  // ---- epilogue: out = max(x - tau, 0), nontemporal store ----
#pragma unroll
  for (int i = 0; i < VEC; ++i) {
    floatx4 o;
    o.x = fmaxf(v[i].x - tau, 0.f);
    o.y = fmaxf(v[i].y - tau, 0.f);
    o.z = fmaxf(v[i].z - tau, 0.f);
    o.w = fmaxf(v[i].w - tau, 0.f);
    __builtin_nontemporal_store(o, &outr[tid + i * BLOCK]);
  }
}

extern "C" void kernel_launch(void* const* d_in, const int* in_sizes, int n_in,
                              void* d_out, int out_size, void* d_ws, size_t ws_size,
                              hipStream_t stream) {
  const float* x = (const float*)d_in[0];
  float* out = (float*)d_out;
  const int rows = in_sizes[0] / D;  // 8192
  sparsemax_kernel<<<rows, BLOCK, 0, stream>>>(x, out);
}